// Round 1
// baseline (588.541 us; speedup 1.0000x reference)
//
#include <hip/hip_runtime.h>

// GCN 2-layer: out = relu(gcnconv(relu(gcnconv(x,W1,b1)), W2, b2))
// Strategy: build CSR-by-dst once per call (int atomics + scan), then
// per-node wave gather with fused self-loop + bias + relu. No float atomics.

#define THREADS 256
#define CHUNK 1024  // scan chunk (4 elems/thread * 256)

__global__ void k_count(const int* __restrict__ dst, int* __restrict__ cnt, int E) {
    int e = blockIdx.x * THREADS + threadIdx.x;
    if (e < E) atomicAdd(&cnt[dst[e]], 1);
}

// Phase 1: per-chunk exclusive scan of cnt -> row_ptr (chunk-local), chunk totals
// -> partials. Also computes dis[i] = rsqrt(1 + cnt[i]).
__global__ void k_scan1(const int* __restrict__ cnt, int* __restrict__ row_ptr,
                        int* __restrict__ partials, float* __restrict__ dis, int n) {
    __shared__ int wsum[4];
    int t = threadIdx.x, lane = t & 63, w = t >> 6;
    int base = blockIdx.x * CHUNK + t * 4;
    int a0 = 0, a1 = 0, a2 = 0, a3 = 0;
    if (base + 0 < n) { a0 = cnt[base + 0]; dis[base + 0] = rsqrtf(1.0f + (float)a0); }
    if (base + 1 < n) { a1 = cnt[base + 1]; dis[base + 1] = rsqrtf(1.0f + (float)a1); }
    if (base + 2 < n) { a2 = cnt[base + 2]; dis[base + 2] = rsqrtf(1.0f + (float)a2); }
    if (base + 3 < n) { a3 = cnt[base + 3]; dis[base + 3] = rsqrtf(1.0f + (float)a3); }
    int s1 = a0, s2 = s1 + a1, s3 = s2 + a2, s4 = s3 + a3;
    int x = s4;
    #pragma unroll
    for (int off = 1; off < 64; off <<= 1) {
        int y = __shfl_up(x, off);
        if (lane >= off) x += y;
    }
    if (lane == 63) wsum[w] = x;
    __syncthreads();
    int woff = 0;
    #pragma unroll
    for (int i = 0; i < 4; ++i) if (i < w) woff += wsum[i];
    int excl = woff + x - s4;  // exclusive prefix for this thread's first element
    if (base + 0 < n) row_ptr[base + 0] = excl;
    if (base + 1 < n) row_ptr[base + 1] = excl + s1;
    if (base + 2 < n) row_ptr[base + 2] = excl + s2;
    if (base + 3 < n) row_ptr[base + 3] = excl + s3;
    if (t == 0) partials[blockIdx.x] = wsum[0] + wsum[1] + wsum[2] + wsum[3];
}

// Phase 2: serial exclusive scan of chunk partials (tiny: ~49 entries).
__global__ void k_scan2(int* partials, int nchunks) {
    if (threadIdx.x == 0 && blockIdx.x == 0) {
        int run = 0;
        for (int i = 0; i < nchunks; ++i) { int v = partials[i]; partials[i] = run; run += v; }
    }
}

// Phase 3: add chunk offsets; duplicate row_ptr into cursor; row_ptr[n] = E.
__global__ void k_scan3(int* __restrict__ row_ptr, const int* __restrict__ partials,
                        int* __restrict__ cursor, int n, int E) {
    int i = blockIdx.x * THREADS + threadIdx.x;
    if (i < n) {
        int v = row_ptr[i] + partials[i >> 10];
        row_ptr[i] = v;
        cursor[i] = v;
    }
    if (i == 0) row_ptr[n] = E;
}

__global__ void k_fill(const int* __restrict__ src, const int* __restrict__ dst,
                       int* __restrict__ cursor, int* __restrict__ csr, int E) {
    int e = blockIdx.x * THREADS + threadIdx.x;
    if (e < E) {
        int d = dst[e];
        int p = atomicAdd(&cursor[d], 1);
        csr[p] = src[e];
    }
}

// Dense GEMM h[n,OUT] = x[n,IN] @ W[IN,OUT], W and x-tile staged in LDS.
template <int IN, int OUT, int BN>
__global__ void k_gemm(const float* __restrict__ x, const float* __restrict__ W,
                       float* __restrict__ h, int n) {
    __shared__ float Ws[IN * OUT];
    __shared__ float xs[BN * IN];
    int t = threadIdx.x;
    for (int i = t; i < IN * OUT; i += THREADS) Ws[i] = W[i];
    int node0 = blockIdx.x * BN;
    for (int i = t; i < BN * IN; i += THREADS) {
        int node = node0 + i / IN;
        xs[i] = (node < n) ? x[(size_t)node * IN + (i % IN)] : 0.0f;
    }
    __syncthreads();
    const int PER = BN * OUT / THREADS;
    #pragma unroll
    for (int r = 0; r < PER; ++r) {
        int o = r * THREADS + t;
        int ln = o / OUT, c = o % OUT;
        float acc = 0.0f;
        #pragma unroll 8
        for (int k = 0; k < IN; ++k) acc += xs[ln * IN + k] * Ws[k * OUT + c];
        int node = node0 + ln;
        if (node < n) h[(size_t)node * OUT + c] = acc;
    }
}

// Per-node gather: one 64-lane wave per node.
// out[i,:] = relu(dis_i * (sum_{e:dst=i} dis_src * h[src,:] + dis_i * h[i,:]) + b)
template <int OUT>
__global__ void k_gather(const float* __restrict__ h, const int* __restrict__ row_ptr,
                         const int* __restrict__ csr, const float* __restrict__ dis,
                         const float* __restrict__ bias, float* __restrict__ out, int n) {
    int wave = threadIdx.x >> 6, lane = threadIdx.x & 63;
    int node = blockIdx.x * 4 + wave;
    if (node >= n) return;
    int beg = row_ptr[node], end = row_ptr[node + 1];
    float di = dis[node];
    if constexpr (OUT == 128) {
        int c = lane * 2;
        float2 hv = *(const float2*)(h + (size_t)node * 128 + c);
        float a0 = di * hv.x, a1 = di * hv.y;
        for (int j = beg; j < end; ++j) {
            int s = csr[j];
            float ds = dis[s];
            float2 v = *(const float2*)(h + (size_t)s * 128 + c);
            a0 += ds * v.x;
            a1 += ds * v.y;
        }
        float b0 = bias[c], b1 = bias[c + 1];
        float o0 = fmaxf(di * a0 + b0, 0.0f);
        float o1 = fmaxf(di * a1 + b1, 0.0f);
        *(float2*)(out + (size_t)node * 128 + c) = make_float2(o0, o1);
    } else {
        int c = lane;
        float a0 = di * h[(size_t)node * 64 + c];
        for (int j = beg; j < end; ++j) {
            int s = csr[j];
            a0 += dis[s] * h[(size_t)s * 64 + c];
        }
        out[(size_t)node * 64 + c] = fmaxf(di * a0 + bias[c], 0.0f);
    }
}

static inline size_t align_up(size_t v, size_t a) { return (v + a - 1) / a * a; }

extern "C" void kernel_launch(void* const* d_in, const int* in_sizes, int n_in,
                              void* d_out, int out_size, void* d_ws, size_t ws_size,
                              hipStream_t stream) {
    const float* x  = (const float*)d_in[0];
    const int*   ei = (const int*)d_in[1];
    const float* W1 = (const float*)d_in[2];
    const float* b1 = (const float*)d_in[3];
    const float* W2 = (const float*)d_in[4];
    const float* b2 = (const float*)d_in[5];
    float* out = (float*)d_out;

    const int N = in_sizes[0] / 64;       // 50000
    const int E = in_sizes[1] / 2;        // 1600000
    const int* src = ei;
    const int* dst = ei + E;

    // workspace layout
    char* ws = (char*)d_ws;
    size_t off = 0;
    int* cnt = (int*)(ws + off);            off = align_up(off + (size_t)N * 4, 256);
    int* row_ptr = (int*)(ws + off);        off = align_up(off + (size_t)(N + 1) * 4, 256);
    int* cursor = (int*)(ws + off);         off = align_up(off + (size_t)N * 4, 256);
    int* partials = (int*)(ws + off);       off = align_up(off + 4096, 256);
    float* dis = (float*)(ws + off);        off = align_up(off + (size_t)N * 4, 256);
    int* csr = (int*)(ws + off);            off = align_up(off + (size_t)E * 4, 256);
    float* h = (float*)(ws + off);          off = align_up(off + (size_t)N * 128 * 4, 256);
    float* y1 = (float*)(ws + off);         off = align_up(off + (size_t)N * 128 * 4, 256);
    (void)ws_size;

    const int nchunks = (N + CHUNK - 1) / CHUNK;

    hipMemsetAsync(cnt, 0, (size_t)N * 4, stream);
    k_count<<<(E + THREADS - 1) / THREADS, THREADS, 0, stream>>>(dst, cnt, E);
    k_scan1<<<nchunks, THREADS, 0, stream>>>(cnt, row_ptr, partials, dis, N);
    k_scan2<<<1, 64, 0, stream>>>(partials, nchunks);
    k_scan3<<<(N + THREADS - 1) / THREADS, THREADS, 0, stream>>>(row_ptr, partials, cursor, N, E);
    k_fill<<<(E + THREADS - 1) / THREADS, THREADS, 0, stream>>>(src, dst, cursor, csr, E);

    // layer 1: h = x @ W1 ; y1 = relu(gather(h) + b1)
    k_gemm<64, 128, 16><<<(N + 15) / 16, THREADS, 0, stream>>>(x, W1, h, N);
    k_gather<128><<<(N + 3) / 4, THREADS, 0, stream>>>(h, row_ptr, csr, dis, b1, y1, N);

    // layer 2: h2 = y1 @ W2 ; out = relu(gather(h2) + b2)  (reuse h buffer)
    k_gemm<128, 64, 16><<<(N + 15) / 16, THREADS, 0, stream>>>(y1, W2, h, N);
    k_gather<64><<<(N + 3) / 4, THREADS, 0, stream>>>(h, row_ptr, csr, dis, b2, out, N);
}

// Round 2
// 428.305 us; speedup vs baseline: 1.3741x; 1.3741x over previous
//
#include <hip/hip_runtime.h>

// GCN 2-layer. CSR-by-dst build (int atomics + scan), register-blocked GEMM
// with fused dis-prescale (g = dis_i * (x@W)), then per-node wave gather with
// shfl-broadcast indices and 8-deep MLP unroll:
//   out_i = relu(dis_i * (g_i + sum_{src in N(i)} g_src) + b)

#define THREADS 256
#define CHUNK 1024  // scan chunk (4 elems/thread * 256)

__global__ void k_count(const int* __restrict__ dst, int* __restrict__ cnt, int E) {
    int e = blockIdx.x * THREADS + threadIdx.x;
    if (e < E) atomicAdd(&cnt[dst[e]], 1);
}

__global__ void k_scan1(const int* __restrict__ cnt, int* __restrict__ row_ptr,
                        int* __restrict__ partials, float* __restrict__ dis, int n) {
    __shared__ int wsum[4];
    int t = threadIdx.x, lane = t & 63, w = t >> 6;
    int base = blockIdx.x * CHUNK + t * 4;
    int a0 = 0, a1 = 0, a2 = 0, a3 = 0;
    if (base + 0 < n) { a0 = cnt[base + 0]; dis[base + 0] = rsqrtf(1.0f + (float)a0); }
    if (base + 1 < n) { a1 = cnt[base + 1]; dis[base + 1] = rsqrtf(1.0f + (float)a1); }
    if (base + 2 < n) { a2 = cnt[base + 2]; dis[base + 2] = rsqrtf(1.0f + (float)a2); }
    if (base + 3 < n) { a3 = cnt[base + 3]; dis[base + 3] = rsqrtf(1.0f + (float)a3); }
    int s1 = a0, s2 = s1 + a1, s3 = s2 + a2, s4 = s3 + a3;
    int x = s4;
    #pragma unroll
    for (int off = 1; off < 64; off <<= 1) {
        int y = __shfl_up(x, off);
        if (lane >= off) x += y;
    }
    if (lane == 63) wsum[w] = x;
    __syncthreads();
    int woff = 0;
    #pragma unroll
    for (int i = 0; i < 4; ++i) if (i < w) woff += wsum[i];
    int excl = woff + x - s4;
    if (base + 0 < n) row_ptr[base + 0] = excl;
    if (base + 1 < n) row_ptr[base + 1] = excl + s1;
    if (base + 2 < n) row_ptr[base + 2] = excl + s2;
    if (base + 3 < n) row_ptr[base + 3] = excl + s3;
    if (t == 0) partials[blockIdx.x] = wsum[0] + wsum[1] + wsum[2] + wsum[3];
}

__global__ void k_scan2(int* partials, int nchunks) {
    if (threadIdx.x == 0 && blockIdx.x == 0) {
        int run = 0;
        for (int i = 0; i < nchunks; ++i) { int v = partials[i]; partials[i] = run; run += v; }
    }
}

__global__ void k_scan3(int* __restrict__ row_ptr, const int* __restrict__ partials,
                        int* __restrict__ cursor, int n, int E) {
    int i = blockIdx.x * THREADS + threadIdx.x;
    if (i < n) {
        int v = row_ptr[i] + partials[i >> 10];
        row_ptr[i] = v;
        cursor[i] = v;
    }
    if (i == 0) row_ptr[n] = E;
}

__global__ void k_fill(const int* __restrict__ src, const int* __restrict__ dst,
                       int* __restrict__ cursor, int* __restrict__ csr, int E) {
    int e = blockIdx.x * THREADS + threadIdx.x;
    if (e < E) {
        int d = dst[e];
        int p = atomicAdd(&cursor[d], 1);
        csr[p] = src[e];
    }
}

// Register-blocked GEMM: g[node, :] = dis[node] * (x[node, :] @ W)
// Block = 64 nodes; thread computes 4 nodes x CPT cols. (OUT/CPT)*(64/4) == 256.
template <int IN, int OUT, int CPT>
__global__ __launch_bounds__(256) void k_gemm(const float* __restrict__ x,
                                              const float* __restrict__ W,
                                              const float* __restrict__ dis,
                                              float* __restrict__ g, int n) {
    constexpr int BN = 64;
    constexpr int XPAD = IN + 4;  // bank-conflict pad, keeps 16B alignment
    __shared__ float xs[BN * XPAD];
    __shared__ float Ws[IN * OUT];
    int t = threadIdx.x;
    for (int i = t; i < IN * OUT; i += 256) Ws[i] = W[i];
    int node0 = blockIdx.x * BN;
    for (int i = t; i < BN * IN; i += 256) {
        int r = i / IN, k = i % IN;
        int node = node0 + r;
        xs[r * XPAD + k] = (node < n) ? x[(size_t)node * IN + k] : 0.0f;
    }
    __syncthreads();
    constexpr int CG = OUT / CPT;     // column groups (16)
    int tc = t % CG, tn = t / CG;     // tn in [0,16)
    int c0 = tc * CPT, nb = tn * 4;
    float acc[4][CPT] = {};
    #pragma unroll 4
    for (int k = 0; k < IN; ++k) {
        float xv0 = xs[(nb + 0) * XPAD + k];
        float xv1 = xs[(nb + 1) * XPAD + k];
        float xv2 = xs[(nb + 2) * XPAD + k];
        float xv3 = xs[(nb + 3) * XPAD + k];
        #pragma unroll
        for (int c = 0; c < CPT; ++c) {
            float w = Ws[k * OUT + c0 + c];
            acc[0][c] += xv0 * w;
            acc[1][c] += xv1 * w;
            acc[2][c] += xv2 * w;
            acc[3][c] += xv3 * w;
        }
    }
    #pragma unroll
    for (int i = 0; i < 4; ++i) {
        int node = node0 + nb + i;
        if (node < n) {
            float d = dis[node];
            #pragma unroll
            for (int c = 0; c < CPT; ++c) g[(size_t)node * OUT + c0 + c] = d * acc[i][c];
        }
    }
}

// Per-node wave gather with shfl-broadcast indices + 8-deep MLP unroll.
// out[i,:] = relu(dis_i * (g[i,:] + sum_{e:dst=i} g[src,:]) + b)
template <int OUT>
__global__ __launch_bounds__(256) void k_gather(const float* __restrict__ g,
                                                const int* __restrict__ row_ptr,
                                                const int* __restrict__ csr,
                                                const float* __restrict__ dis,
                                                const float* __restrict__ bias,
                                                float* __restrict__ out, int n) {
    int wave = threadIdx.x >> 6, lane = threadIdx.x & 63;
    int node = blockIdx.x * 4 + wave;
    if (node >= n) return;
    int beg = row_ptr[node], end = row_ptr[node + 1];
    float di = dis[node];
    if constexpr (OUT == 128) {
        const float2* gp = (const float2*)g;  // row stride = 64 float2
        float2 self = gp[(size_t)node * 64 + lane];
        float a0 = self.x, a1 = self.y;
        for (int base = beg; base < end; base += 64) {
            int m = end - base; if (m > 64) m = 64;
            int idx = csr[base + (lane < m ? lane : 0)];
            int t = 0;
            for (; t + 8 <= m; t += 8) {
                int s0 = __shfl(idx, t + 0), s1 = __shfl(idx, t + 1);
                int s2 = __shfl(idx, t + 2), s3 = __shfl(idx, t + 3);
                int s4 = __shfl(idx, t + 4), s5 = __shfl(idx, t + 5);
                int s6 = __shfl(idx, t + 6), s7 = __shfl(idx, t + 7);
                float2 v0 = gp[(size_t)s0 * 64 + lane];
                float2 v1 = gp[(size_t)s1 * 64 + lane];
                float2 v2 = gp[(size_t)s2 * 64 + lane];
                float2 v3 = gp[(size_t)s3 * 64 + lane];
                float2 v4 = gp[(size_t)s4 * 64 + lane];
                float2 v5 = gp[(size_t)s5 * 64 + lane];
                float2 v6 = gp[(size_t)s6 * 64 + lane];
                float2 v7 = gp[(size_t)s7 * 64 + lane];
                a0 += ((v0.x + v1.x) + (v2.x + v3.x)) + ((v4.x + v5.x) + (v6.x + v7.x));
                a1 += ((v0.y + v1.y) + (v2.y + v3.y)) + ((v4.y + v5.y) + (v6.y + v7.y));
            }
            for (; t < m; ++t) {
                int s = __shfl(idx, t);
                float2 v = gp[(size_t)s * 64 + lane];
                a0 += v.x; a1 += v.y;
            }
        }
        int c = lane * 2;
        float o0 = fmaxf(di * a0 + bias[c], 0.0f);
        float o1 = fmaxf(di * a1 + bias[c + 1], 0.0f);
        ((float2*)out)[(size_t)node * 64 + lane] = make_float2(o0, o1);
    } else {
        float a0 = g[(size_t)node * 64 + lane];
        for (int base = beg; base < end; base += 64) {
            int m = end - base; if (m > 64) m = 64;
            int idx = csr[base + (lane < m ? lane : 0)];
            int t = 0;
            for (; t + 8 <= m; t += 8) {
                int s0 = __shfl(idx, t + 0), s1 = __shfl(idx, t + 1);
                int s2 = __shfl(idx, t + 2), s3 = __shfl(idx, t + 3);
                int s4 = __shfl(idx, t + 4), s5 = __shfl(idx, t + 5);
                int s6 = __shfl(idx, t + 6), s7 = __shfl(idx, t + 7);
                float v0 = g[(size_t)s0 * 64 + lane];
                float v1 = g[(size_t)s1 * 64 + lane];
                float v2 = g[(size_t)s2 * 64 + lane];
                float v3 = g[(size_t)s3 * 64 + lane];
                float v4 = g[(size_t)s4 * 64 + lane];
                float v5 = g[(size_t)s5 * 64 + lane];
                float v6 = g[(size_t)s6 * 64 + lane];
                float v7 = g[(size_t)s7 * 64 + lane];
                a0 += ((v0 + v1) + (v2 + v3)) + ((v4 + v5) + (v6 + v7));
            }
            for (; t < m; ++t) {
                int s = __shfl(idx, t);
                a0 += g[(size_t)s * 64 + lane];
            }
        }
        out[(size_t)node * 64 + lane] = fmaxf(di * a0 + bias[lane], 0.0f);
    }
}

static inline size_t align_up(size_t v, size_t a) { return (v + a - 1) / a * a; }

extern "C" void kernel_launch(void* const* d_in, const int* in_sizes, int n_in,
                              void* d_out, int out_size, void* d_ws, size_t ws_size,
                              hipStream_t stream) {
    const float* x  = (const float*)d_in[0];
    const int*   ei = (const int*)d_in[1];
    const float* W1 = (const float*)d_in[2];
    const float* b1 = (const float*)d_in[3];
    const float* W2 = (const float*)d_in[4];
    const float* b2 = (const float*)d_in[5];
    float* out = (float*)d_out;

    const int N = in_sizes[0] / 64;   // 50000
    const int E = in_sizes[1] / 2;    // 1600000
    const int* src = ei;
    const int* dst = ei + E;

    char* ws = (char*)d_ws;
    size_t off = 0;
    int* cnt = (int*)(ws + off);      off = align_up(off + (size_t)N * 4, 256);
    int* row_ptr = (int*)(ws + off);  off = align_up(off + (size_t)(N + 1) * 4, 256);
    int* cursor = (int*)(ws + off);   off = align_up(off + (size_t)N * 4, 256);
    int* partials = (int*)(ws + off); off = align_up(off + 4096, 256);
    float* dis = (float*)(ws + off);  off = align_up(off + (size_t)N * 4, 256);
    int* csr = (int*)(ws + off);      off = align_up(off + (size_t)E * 4, 256);
    float* g = (float*)(ws + off);    off = align_up(off + (size_t)N * 128 * 4, 256);
    float* y1 = (float*)(ws + off);   off = align_up(off + (size_t)N * 128 * 4, 256);
    (void)ws_size;

    const int nchunks = (N + CHUNK - 1) / CHUNK;

    hipMemsetAsync(cnt, 0, (size_t)N * 4, stream);
    k_count<<<(E + THREADS - 1) / THREADS, THREADS, 0, stream>>>(dst, cnt, E);
    k_scan1<<<nchunks, THREADS, 0, stream>>>(cnt, row_ptr, partials, dis, N);
    k_scan2<<<1, 64, 0, stream>>>(partials, nchunks);
    k_scan3<<<(N + THREADS - 1) / THREADS, THREADS, 0, stream>>>(row_ptr, partials, cursor, N, E);
    k_fill<<<(E + THREADS - 1) / THREADS, THREADS, 0, stream>>>(src, dst, cursor, csr, E);

    // layer 1: g = dis * (x @ W1) ; y1 = relu(dis * (g_i + sum g_src) + b1)
    k_gemm<64, 128, 8><<<(N + 63) / 64, THREADS, 0, stream>>>(x, W1, dis, g, N);
    k_gather<128><<<(N + 3) / 4, THREADS, 0, stream>>>(g, row_ptr, csr, dis, b1, y1, N);

    // layer 2: g = dis * (y1 @ W2) ; out = relu(dis * (g_i + sum g_src) + b2)
    k_gemm<128, 64, 4><<<(N + 63) / 64, THREADS, 0, stream>>>(y1, W2, dis, g, N);
    k_gather<64><<<(N + 3) / 4, THREADS, 0, stream>>>(g, row_ptr, csr, dis, b2, out, N);
}

// Round 3
// 365.647 us; speedup vs baseline: 1.6096x; 1.1714x over previous
//
#include <hip/hip_runtime.h>
#include <hip/hip_fp16.h>

// GCN 2-layer. CSR-by-dst build (int atomics + scan), register-blocked GEMM
// with fused dis-prescale (g = dis_i * (x@W)) stored as fp16, then per-node
// wave gather (shfl-broadcast indices, 8-deep MLP unroll):
//   out_i = relu(dis_i * (g_i + sum_{src in N(i)} g_src) + b)

#define THREADS 256
#define CHUNK 1024  // scan chunk (4 elems/thread * 256)

__global__ void k_count(const int* __restrict__ dst, int* __restrict__ cnt, int E) {
    int e = blockIdx.x * THREADS + threadIdx.x;
    if (e < E) atomicAdd(&cnt[dst[e]], 1);
}

__global__ void k_scan1(const int* __restrict__ cnt, int* __restrict__ row_ptr,
                        int* __restrict__ partials, float* __restrict__ dis, int n) {
    __shared__ int wsum[4];
    int t = threadIdx.x, lane = t & 63, w = t >> 6;
    int base = blockIdx.x * CHUNK + t * 4;
    int a0 = 0, a1 = 0, a2 = 0, a3 = 0;
    if (base + 0 < n) { a0 = cnt[base + 0]; dis[base + 0] = rsqrtf(1.0f + (float)a0); }
    if (base + 1 < n) { a1 = cnt[base + 1]; dis[base + 1] = rsqrtf(1.0f + (float)a1); }
    if (base + 2 < n) { a2 = cnt[base + 2]; dis[base + 2] = rsqrtf(1.0f + (float)a2); }
    if (base + 3 < n) { a3 = cnt[base + 3]; dis[base + 3] = rsqrtf(1.0f + (float)a3); }
    int s1 = a0, s2 = s1 + a1, s3 = s2 + a2, s4 = s3 + a3;
    int x = s4;
    #pragma unroll
    for (int off = 1; off < 64; off <<= 1) {
        int y = __shfl_up(x, off);
        if (lane >= off) x += y;
    }
    if (lane == 63) wsum[w] = x;
    __syncthreads();
    int woff = 0;
    #pragma unroll
    for (int i = 0; i < 4; ++i) if (i < w) woff += wsum[i];
    int excl = woff + x - s4;
    if (base + 0 < n) row_ptr[base + 0] = excl;
    if (base + 1 < n) row_ptr[base + 1] = excl + s1;
    if (base + 2 < n) row_ptr[base + 2] = excl + s2;
    if (base + 3 < n) row_ptr[base + 3] = excl + s3;
    if (t == 0) partials[blockIdx.x] = wsum[0] + wsum[1] + wsum[2] + wsum[3];
}

__global__ void k_scan2(int* partials, int nchunks) {
    if (threadIdx.x == 0 && blockIdx.x == 0) {
        int run = 0;
        for (int i = 0; i < nchunks; ++i) { int v = partials[i]; partials[i] = run; run += v; }
    }
}

__global__ void k_scan3(int* __restrict__ row_ptr, const int* __restrict__ partials,
                        int* __restrict__ cursor, int n, int E) {
    int i = blockIdx.x * THREADS + threadIdx.x;
    if (i < n) {
        int v = row_ptr[i] + partials[i >> 10];
        row_ptr[i] = v;
        cursor[i] = v;
    }
    if (i == 0) row_ptr[n] = E;
}

__global__ void k_fill(const int* __restrict__ src, const int* __restrict__ dst,
                       int* __restrict__ cursor, int* __restrict__ csr, int E) {
    int e = blockIdx.x * THREADS + threadIdx.x;
    if (e < E) {
        int d = dst[e];
        int p = atomicAdd(&cursor[d], 1);
        csr[p] = src[e];
    }
}

// Register-blocked GEMM: g[node, :] = half( dis[node] * (x[node, :] @ W) )
// Block = 64 nodes; thread computes 4 nodes x CPT cols. (OUT/CPT)*(64/4) == 256.
template <int IN, int OUT, int CPT>
__global__ __launch_bounds__(256) void k_gemm(const float* __restrict__ x,
                                              const float* __restrict__ W,
                                              const float* __restrict__ dis,
                                              __half* __restrict__ g, int n) {
    constexpr int BN = 64;
    constexpr int XPAD = IN + 4;
    __shared__ float xs[BN * XPAD];
    __shared__ float Ws[IN * OUT];
    int t = threadIdx.x;
    for (int i = t; i < IN * OUT; i += 256) Ws[i] = W[i];
    int node0 = blockIdx.x * BN;
    for (int i = t; i < BN * IN; i += 256) {
        int r = i / IN, k = i % IN;
        int node = node0 + r;
        xs[r * XPAD + k] = (node < n) ? x[(size_t)node * IN + k] : 0.0f;
    }
    __syncthreads();
    constexpr int CG = OUT / CPT;
    int tc = t % CG, tn = t / CG;
    int c0 = tc * CPT, nb = tn * 4;
    float acc[4][CPT] = {};
    #pragma unroll 4
    for (int k = 0; k < IN; ++k) {
        float xv0 = xs[(nb + 0) * XPAD + k];
        float xv1 = xs[(nb + 1) * XPAD + k];
        float xv2 = xs[(nb + 2) * XPAD + k];
        float xv3 = xs[(nb + 3) * XPAD + k];
        #pragma unroll
        for (int c = 0; c < CPT; ++c) {
            float w = Ws[k * OUT + c0 + c];
            acc[0][c] += xv0 * w;
            acc[1][c] += xv1 * w;
            acc[2][c] += xv2 * w;
            acc[3][c] += xv3 * w;
        }
    }
    #pragma unroll
    for (int i = 0; i < 4; ++i) {
        int node = node0 + nb + i;
        if (node < n) {
            float d = dis[node];
            #pragma unroll
            for (int c = 0; c < CPT; c += 2) {
                __half2 hv = __floats2half2_rn(d * acc[i][c], d * acc[i][c + 1]);
                *(__half2*)(&g[(size_t)node * OUT + c0 + c]) = hv;
            }
        }
    }
}

// Per-node wave gather with shfl-broadcast indices + 8-deep MLP unroll.
// out[i,:] = relu(dis_i * (g[i,:] + sum_{e:dst=i} g[src,:]) + b)
template <int OUT>
__global__ __launch_bounds__(256) void k_gather(const __half* __restrict__ g,
                                                const int* __restrict__ row_ptr,
                                                const int* __restrict__ csr,
                                                const float* __restrict__ dis,
                                                const float* __restrict__ bias,
                                                float* __restrict__ out, int n) {
    int wave = threadIdx.x >> 6, lane = threadIdx.x & 63;
    int node = blockIdx.x * 4 + wave;
    if (node >= n) return;
    int beg = row_ptr[node], end = row_ptr[node + 1];
    float di = dis[node];
    if constexpr (OUT == 128) {
        const __half2* gp = (const __half2*)g;  // row stride = 64 half2
        float2 self = __half22float2(gp[(size_t)node * 64 + lane]);
        float a0 = self.x, a1 = self.y;
        for (int base = beg; base < end; base += 64) {
            int m = end - base; if (m > 64) m = 64;
            int idx = csr[base + (lane < m ? lane : 0)];
            int t = 0;
            for (; t + 8 <= m; t += 8) {
                int s0 = __shfl(idx, t + 0), s1 = __shfl(idx, t + 1);
                int s2 = __shfl(idx, t + 2), s3 = __shfl(idx, t + 3);
                int s4 = __shfl(idx, t + 4), s5 = __shfl(idx, t + 5);
                int s6 = __shfl(idx, t + 6), s7 = __shfl(idx, t + 7);
                float2 v0 = __half22float2(gp[(size_t)s0 * 64 + lane]);
                float2 v1 = __half22float2(gp[(size_t)s1 * 64 + lane]);
                float2 v2 = __half22float2(gp[(size_t)s2 * 64 + lane]);
                float2 v3 = __half22float2(gp[(size_t)s3 * 64 + lane]);
                float2 v4 = __half22float2(gp[(size_t)s4 * 64 + lane]);
                float2 v5 = __half22float2(gp[(size_t)s5 * 64 + lane]);
                float2 v6 = __half22float2(gp[(size_t)s6 * 64 + lane]);
                float2 v7 = __half22float2(gp[(size_t)s7 * 64 + lane]);
                a0 += ((v0.x + v1.x) + (v2.x + v3.x)) + ((v4.x + v5.x) + (v6.x + v7.x));
                a1 += ((v0.y + v1.y) + (v2.y + v3.y)) + ((v4.y + v5.y) + (v6.y + v7.y));
            }
            for (; t < m; ++t) {
                int s = __shfl(idx, t);
                float2 v = __half22float2(gp[(size_t)s * 64 + lane]);
                a0 += v.x; a1 += v.y;
            }
        }
        int c = lane * 2;
        float o0 = fmaxf(di * a0 + bias[c], 0.0f);
        float o1 = fmaxf(di * a1 + bias[c + 1], 0.0f);
        ((float2*)out)[(size_t)node * 64 + lane] = make_float2(o0, o1);
    } else {
        float a0 = __half2float(g[(size_t)node * 64 + lane]);
        for (int base = beg; base < end; base += 64) {
            int m = end - base; if (m > 64) m = 64;
            int idx = csr[base + (lane < m ? lane : 0)];
            int t = 0;
            for (; t + 8 <= m; t += 8) {
                int s0 = __shfl(idx, t + 0), s1 = __shfl(idx, t + 1);
                int s2 = __shfl(idx, t + 2), s3 = __shfl(idx, t + 3);
                int s4 = __shfl(idx, t + 4), s5 = __shfl(idx, t + 5);
                int s6 = __shfl(idx, t + 6), s7 = __shfl(idx, t + 7);
                float v0 = __half2float(g[(size_t)s0 * 64 + lane]);
                float v1 = __half2float(g[(size_t)s1 * 64 + lane]);
                float v2 = __half2float(g[(size_t)s2 * 64 + lane]);
                float v3 = __half2float(g[(size_t)s3 * 64 + lane]);
                float v4 = __half2float(g[(size_t)s4 * 64 + lane]);
                float v5 = __half2float(g[(size_t)s5 * 64 + lane]);
                float v6 = __half2float(g[(size_t)s6 * 64 + lane]);
                float v7 = __half2float(g[(size_t)s7 * 64 + lane]);
                a0 += ((v0 + v1) + (v2 + v3)) + ((v4 + v5) + (v6 + v7));
            }
            for (; t < m; ++t) {
                int s = __shfl(idx, t);
                a0 += __half2float(g[(size_t)s * 64 + lane]);
            }
        }
        out[(size_t)node * 64 + lane] = fmaxf(di * a0 + bias[lane], 0.0f);
    }
}

static inline size_t align_up(size_t v, size_t a) { return (v + a - 1) / a * a; }

extern "C" void kernel_launch(void* const* d_in, const int* in_sizes, int n_in,
                              void* d_out, int out_size, void* d_ws, size_t ws_size,
                              hipStream_t stream) {
    const float* x  = (const float*)d_in[0];
    const int*   ei = (const int*)d_in[1];
    const float* W1 = (const float*)d_in[2];
    const float* b1 = (const float*)d_in[3];
    const float* W2 = (const float*)d_in[4];
    const float* b2 = (const float*)d_in[5];
    float* out = (float*)d_out;

    const int N = in_sizes[0] / 64;   // 50000
    const int E = in_sizes[1] / 2;    // 1600000
    const int* src = ei;
    const int* dst = ei + E;

    char* ws = (char*)d_ws;
    size_t off = 0;
    int* cnt = (int*)(ws + off);      off = align_up(off + (size_t)N * 4, 256);
    int* row_ptr = (int*)(ws + off);  off = align_up(off + (size_t)(N + 1) * 4, 256);
    int* cursor = (int*)(ws + off);   off = align_up(off + (size_t)N * 4, 256);
    int* partials = (int*)(ws + off); off = align_up(off + 4096, 256);
    float* dis = (float*)(ws + off);  off = align_up(off + (size_t)N * 4, 256);
    int* csr = (int*)(ws + off);      off = align_up(off + (size_t)E * 4, 256);
    __half* g = (__half*)(ws + off);  off = align_up(off + (size_t)N * 128 * 2, 256);
    float* y1 = (float*)(ws + off);   off = align_up(off + (size_t)N * 128 * 4, 256);
    (void)ws_size;

    const int nchunks = (N + CHUNK - 1) / CHUNK;

    hipMemsetAsync(cnt, 0, (size_t)N * 4, stream);
    k_count<<<(E + THREADS - 1) / THREADS, THREADS, 0, stream>>>(dst, cnt, E);
    k_scan1<<<nchunks, THREADS, 0, stream>>>(cnt, row_ptr, partials, dis, N);
    k_scan2<<<1, 64, 0, stream>>>(partials, nchunks);
    k_scan3<<<(N + THREADS - 1) / THREADS, THREADS, 0, stream>>>(row_ptr, partials, cursor, N, E);
    k_fill<<<(E + THREADS - 1) / THREADS, THREADS, 0, stream>>>(src, dst, cursor, csr, E);

    // layer 1: g = half(dis * (x @ W1)) ; y1 = relu(dis * (g_i + sum g_src) + b1)
    k_gemm<64, 128, 8><<<(N + 63) / 64, THREADS, 0, stream>>>(x, W1, dis, g, N);
    k_gather<128><<<(N + 3) / 4, THREADS, 0, stream>>>(g, row_ptr, csr, dis, b1, y1, N);

    // layer 2: g = half(dis * (y1 @ W2)) ; out = relu(dis * (g_i + sum g_src) + b2)
    k_gemm<128, 64, 4><<<(N + 63) / 64, THREADS, 0, stream>>>(y1, W2, dis, g, N);
    k_gather<64><<<(N + 3) / 4, THREADS, 0, stream>>>(g, row_ptr, csr, dis, b2, out, N);
}

// Round 4
// 214.410 us; speedup vs baseline: 2.7449x; 1.7054x over previous
//
#include <hip/hip_runtime.h>
#include <hip/hip_fp16.h>

// GCN 2-layer. CSR-by-dst via 2-level LDS counting sort (no per-edge global
// scatter), register-blocked GEMM with fused dis-prescale (g = dis_i*(x@W),
// fp16), per-node wave gather (shfl-broadcast indices, 8-deep MLP unroll):
//   out_i = relu(dis_i * (g_i + sum_{src in N(i)} g_src) + b)
// Requires N < 65536 so an edge packs into u32 (dst<<16 | src).

#define THREADS 256
#define EPB_HIST 16384  // edges/block in hist
#define EPB_PART 8192   // edges/block in partition (32 KB u32 stage)
#define MAXB 16384      // stage capacity in place (mean 8192, +91 sigma)

// exclusive prefix for v across the 256-thread block (4 waves)
__device__ inline int block_scan256(int v, int* wsum) {
    int lane = threadIdx.x & 63, w = threadIdx.x >> 6;
    int x = v;
    #pragma unroll
    for (int off = 1; off < 64; off <<= 1) {
        int y = __shfl_up(x, off);
        if (lane >= off) x += y;
    }
    if (lane == 63) wsum[w] = x;
    __syncthreads();
    int woff = 0;
    #pragma unroll
    for (int i = 0; i < 4; ++i) if (i < w) woff += wsum[i];
    return woff + x - v;
}

__global__ __launch_bounds__(256) void k_hist(const int* __restrict__ dst,
                                              int* __restrict__ bucketCnt, int E, int NB) {
    __shared__ int h[256];
    int t = threadIdx.x;
    h[t] = 0;
    __syncthreads();
    int base = blockIdx.x * EPB_HIST;
    int end = min(base + EPB_HIST, E);
    for (int e = base + t; e < end; e += 256) atomicAdd(&h[dst[e] >> 8], 1);
    __syncthreads();
    if (t < NB && h[t]) atomicAdd(&bucketCnt[t], h[t]);
}

__global__ __launch_bounds__(256) void k_bucket_scan(const int* __restrict__ bucketCnt,
                                                     int* __restrict__ bucketBase,
                                                     int* __restrict__ bucketCursor,
                                                     int NB, int E) {
    __shared__ int wsum[4];
    int t = threadIdx.x;
    int v = (t < NB) ? bucketCnt[t] : 0;
    int excl = block_scan256(v, wsum);
    if (t < NB) { bucketBase[t] = excl; bucketCursor[t] = excl; }
    if (t == 0) bucketBase[NB] = E;
}

__global__ __launch_bounds__(256) void k_partition(const int* __restrict__ src,
                                                   const int* __restrict__ dst,
                                                   int* __restrict__ bucketCursor,
                                                   unsigned int* __restrict__ bucketed, int E) {
    __shared__ int hist[256];
    __shared__ int localOff[256];
    __shared__ int runBase[256];
    __shared__ int wsum[4];
    __shared__ unsigned int stage[EPB_PART];
    int t = threadIdx.x;
    int base = blockIdx.x * EPB_PART;
    int nE = min(EPB_PART, E - base);
    hist[t] = 0;
    __syncthreads();
    for (int j = t; j < nE; j += 256) atomicAdd(&hist[dst[base + j] >> 8], 1);
    __syncthreads();
    int v = hist[t];
    int excl = block_scan256(v, wsum);
    localOff[t] = excl;
    if (v > 0) runBase[t] = atomicAdd(&bucketCursor[t], v);
    __syncthreads();
    hist[t] = excl;  // reuse as in-block cursor
    __syncthreads();
    for (int j = t; j < nE; j += 256) {
        int d = dst[base + j], s = src[base + j];
        int idx = atomicAdd(&hist[d >> 8], 1);
        stage[idx] = ((unsigned)d << 16) | (unsigned)s;
    }
    __syncthreads();
    for (int j = t; j < nE; j += 256) {
        unsigned u = stage[j];
        int b = u >> 24;  // == dst>>8 since dst<65536
        bucketed[runBase[b] + (j - localOff[b])] = u;
    }
}

__global__ __launch_bounds__(256) void k_place(const unsigned int* __restrict__ bucketed,
                                               const int* __restrict__ bucketBase,
                                               unsigned short* __restrict__ csr,
                                               int* __restrict__ row_ptr,
                                               float* __restrict__ dis, int N, int E) {
    __shared__ int nodeCnt[256];
    __shared__ int wsum[4];
    __shared__ unsigned short outS[MAXB];
    int b = blockIdx.x, t = threadIdx.x;
    int base = bucketBase[b];
    int cnt = bucketBase[b + 1] - base;
    nodeCnt[t] = 0;
    __syncthreads();
    for (int j = t; j < cnt; j += 256)
        atomicAdd(&nodeCnt[(bucketed[base + j] >> 16) & 255], 1);
    __syncthreads();
    int v = nodeCnt[t];
    int excl = block_scan256(v, wsum);
    int node = b * 256 + t;
    if (node < N) {
        row_ptr[node] = base + excl;
        dis[node] = rsqrtf(1.0f + (float)v);
        if (node == N - 1) row_ptr[N] = E;
    }
    __syncthreads();
    nodeCnt[t] = excl;  // reuse as cursor
    __syncthreads();
    for (int j = t; j < cnt; j += 256) {
        unsigned u = bucketed[base + j];
        int p = atomicAdd(&nodeCnt[(u >> 16) & 255], 1);
        if (p < MAXB) outS[p] = (unsigned short)(u & 0xFFFF);
    }
    __syncthreads();
    for (int j = t; j < cnt; j += 256) csr[base + j] = outS[j];
}

// Register-blocked GEMM: g[node, :] = half( dis[node] * (x[node, :] @ W) )
template <int IN, int OUT, int CPT>
__global__ __launch_bounds__(256) void k_gemm(const float* __restrict__ x,
                                              const float* __restrict__ W,
                                              const float* __restrict__ dis,
                                              __half* __restrict__ g, int n) {
    constexpr int BN = 64;
    constexpr int XPAD = IN + 4;
    __shared__ float xs[BN * XPAD];
    __shared__ float Ws[IN * OUT];
    int t = threadIdx.x;
    for (int i = t; i < IN * OUT; i += 256) Ws[i] = W[i];
    int node0 = blockIdx.x * BN;
    for (int i = t; i < BN * IN; i += 256) {
        int r = i / IN, k = i % IN;
        int node = node0 + r;
        xs[r * XPAD + k] = (node < n) ? x[(size_t)node * IN + k] : 0.0f;
    }
    __syncthreads();
    constexpr int CG = OUT / CPT;
    int tc = t % CG, tn = t / CG;
    int c0 = tc * CPT, nb = tn * 4;
    float acc[4][CPT] = {};
    #pragma unroll 4
    for (int k = 0; k < IN; ++k) {
        float xv0 = xs[(nb + 0) * XPAD + k];
        float xv1 = xs[(nb + 1) * XPAD + k];
        float xv2 = xs[(nb + 2) * XPAD + k];
        float xv3 = xs[(nb + 3) * XPAD + k];
        #pragma unroll
        for (int c = 0; c < CPT; ++c) {
            float w = Ws[k * OUT + c0 + c];
            acc[0][c] += xv0 * w;
            acc[1][c] += xv1 * w;
            acc[2][c] += xv2 * w;
            acc[3][c] += xv3 * w;
        }
    }
    #pragma unroll
    for (int i = 0; i < 4; ++i) {
        int node = node0 + nb + i;
        if (node < n) {
            float d = dis[node];
            #pragma unroll
            for (int c = 0; c < CPT; c += 2) {
                __half2 hv = __floats2half2_rn(d * acc[i][c], d * acc[i][c + 1]);
                *(__half2*)(&g[(size_t)node * OUT + c0 + c]) = hv;
            }
        }
    }
}

// Per-node wave gather with shfl-broadcast indices + 8-deep MLP unroll.
template <int OUT>
__global__ __launch_bounds__(256) void k_gather(const __half* __restrict__ g,
                                                const int* __restrict__ row_ptr,
                                                const unsigned short* __restrict__ csr,
                                                const float* __restrict__ dis,
                                                const float* __restrict__ bias,
                                                float* __restrict__ out, int n) {
    int wave = threadIdx.x >> 6, lane = threadIdx.x & 63;
    int node = blockIdx.x * 4 + wave;
    if (node >= n) return;
    int beg = row_ptr[node], end = row_ptr[node + 1];
    float di = dis[node];
    if constexpr (OUT == 128) {
        const __half2* gp = (const __half2*)g;  // row stride = 64 half2
        float2 self = __half22float2(gp[(size_t)node * 64 + lane]);
        float a0 = self.x, a1 = self.y;
        for (int base = beg; base < end; base += 64) {
            int m = end - base; if (m > 64) m = 64;
            int idx = csr[base + (lane < m ? lane : 0)];
            int t = 0;
            for (; t + 8 <= m; t += 8) {
                int s0 = __shfl(idx, t + 0), s1 = __shfl(idx, t + 1);
                int s2 = __shfl(idx, t + 2), s3 = __shfl(idx, t + 3);
                int s4 = __shfl(idx, t + 4), s5 = __shfl(idx, t + 5);
                int s6 = __shfl(idx, t + 6), s7 = __shfl(idx, t + 7);
                float2 v0 = __half22float2(gp[(size_t)s0 * 64 + lane]);
                float2 v1 = __half22float2(gp[(size_t)s1 * 64 + lane]);
                float2 v2 = __half22float2(gp[(size_t)s2 * 64 + lane]);
                float2 v3 = __half22float2(gp[(size_t)s3 * 64 + lane]);
                float2 v4 = __half22float2(gp[(size_t)s4 * 64 + lane]);
                float2 v5 = __half22float2(gp[(size_t)s5 * 64 + lane]);
                float2 v6 = __half22float2(gp[(size_t)s6 * 64 + lane]);
                float2 v7 = __half22float2(gp[(size_t)s7 * 64 + lane]);
                a0 += ((v0.x + v1.x) + (v2.x + v3.x)) + ((v4.x + v5.x) + (v6.x + v7.x));
                a1 += ((v0.y + v1.y) + (v2.y + v3.y)) + ((v4.y + v5.y) + (v6.y + v7.y));
            }
            for (; t < m; ++t) {
                int s = __shfl(idx, t);
                float2 v = __half22float2(gp[(size_t)s * 64 + lane]);
                a0 += v.x; a1 += v.y;
            }
        }
        int c = lane * 2;
        float o0 = fmaxf(di * a0 + bias[c], 0.0f);
        float o1 = fmaxf(di * a1 + bias[c + 1], 0.0f);
        ((float2*)out)[(size_t)node * 64 + lane] = make_float2(o0, o1);
    } else {
        float a0 = __half2float(g[(size_t)node * 64 + lane]);
        for (int base = beg; base < end; base += 64) {
            int m = end - base; if (m > 64) m = 64;
            int idx = csr[base + (lane < m ? lane : 0)];
            int t = 0;
            for (; t + 8 <= m; t += 8) {
                int s0 = __shfl(idx, t + 0), s1 = __shfl(idx, t + 1);
                int s2 = __shfl(idx, t + 2), s3 = __shfl(idx, t + 3);
                int s4 = __shfl(idx, t + 4), s5 = __shfl(idx, t + 5);
                int s6 = __shfl(idx, t + 6), s7 = __shfl(idx, t + 7);
                float v0 = __half2float(g[(size_t)s0 * 64 + lane]);
                float v1 = __half2float(g[(size_t)s1 * 64 + lane]);
                float v2 = __half2float(g[(size_t)s2 * 64 + lane]);
                float v3 = __half2float(g[(size_t)s3 * 64 + lane]);
                float v4 = __half2float(g[(size_t)s4 * 64 + lane]);
                float v5 = __half2float(g[(size_t)s5 * 64 + lane]);
                float v6 = __half2float(g[(size_t)s6 * 64 + lane]);
                float v7 = __half2float(g[(size_t)s7 * 64 + lane]);
                a0 += ((v0 + v1) + (v2 + v3)) + ((v4 + v5) + (v6 + v7));
            }
            for (; t < m; ++t) {
                int s = __shfl(idx, t);
                a0 += __half2float(g[(size_t)s * 64 + lane]);
            }
        }
        out[(size_t)node * 64 + lane] = fmaxf(di * a0 + bias[lane], 0.0f);
    }
}

static inline size_t align_up(size_t v, size_t a) { return (v + a - 1) / a * a; }

extern "C" void kernel_launch(void* const* d_in, const int* in_sizes, int n_in,
                              void* d_out, int out_size, void* d_ws, size_t ws_size,
                              hipStream_t stream) {
    const float* x  = (const float*)d_in[0];
    const int*   ei = (const int*)d_in[1];
    const float* W1 = (const float*)d_in[2];
    const float* b1 = (const float*)d_in[3];
    const float* W2 = (const float*)d_in[4];
    const float* b2 = (const float*)d_in[5];
    float* out = (float*)d_out;

    const int N = in_sizes[0] / 64;   // 50000
    const int E = in_sizes[1] / 2;    // 1600000
    const int* src = ei;
    const int* dst = ei + E;
    const int NB = (N + 255) >> 8;    // 196 coarse buckets

    char* ws = (char*)d_ws;
    size_t off = 0;
    int* bucketCnt = (int*)(ws + off);      off = align_up(off + (size_t)NB * 4, 256);
    int* bucketBase = (int*)(ws + off);     off = align_up(off + (size_t)(NB + 1) * 4, 256);
    int* bucketCursor = (int*)(ws + off);   off = align_up(off + (size_t)NB * 4, 256);
    unsigned int* bucketed = (unsigned int*)(ws + off); off = align_up(off + (size_t)E * 4, 256);
    unsigned short* csr = (unsigned short*)(ws + off);  off = align_up(off + (size_t)E * 2, 256);
    int* row_ptr = (int*)(ws + off);        off = align_up(off + (size_t)(N + 1) * 4, 256);
    float* dis = (float*)(ws + off);        off = align_up(off + (size_t)N * 4, 256);
    __half* g = (__half*)(ws + off);        off = align_up(off + (size_t)N * 128 * 2, 256);
    float* y1 = (float*)(ws + off);         off = align_up(off + (size_t)N * 128 * 4, 256);
    (void)ws_size;

    hipMemsetAsync(bucketCnt, 0, (size_t)NB * 4, stream);
    k_hist<<<(E + EPB_HIST - 1) / EPB_HIST, THREADS, 0, stream>>>(dst, bucketCnt, E, NB);
    k_bucket_scan<<<1, THREADS, 0, stream>>>(bucketCnt, bucketBase, bucketCursor, NB, E);
    k_partition<<<(E + EPB_PART - 1) / EPB_PART, THREADS, 0, stream>>>(src, dst, bucketCursor, bucketed, E);
    k_place<<<NB, THREADS, 0, stream>>>(bucketed, bucketBase, csr, row_ptr, dis, N, E);

    // layer 1: g = half(dis * (x @ W1)) ; y1 = relu(dis * (g_i + sum g_src) + b1)
    k_gemm<64, 128, 8><<<(N + 63) / 64, THREADS, 0, stream>>>(x, W1, dis, g, N);
    k_gather<128><<<(N + 3) / 4, THREADS, 0, stream>>>(g, row_ptr, csr, dis, b1, y1, N);

    // layer 2: g = half(dis * (y1 @ W2)) ; out = relu(dis * (g_i + sum g_src) + b2)
    k_gemm<128, 64, 4><<<(N + 63) / 64, THREADS, 0, stream>>>(y1, W2, dis, g, N);
    k_gather<64><<<(N + 3) / 4, THREADS, 0, stream>>>(g, row_ptr, csr, dis, b2, out, N);
}